// Round 1
// baseline (9501.316 us; speedup 1.0000x reference)
//
#include <hip/hip_runtime.h>
#include <math.h>

#define BB   64
#define CC   862
#define FB   257
#define DM   256
#define DFF  512
#define NIMG 128
#define ROWS_RE (BB*CC)        // 55168
#define ROWS_ALL (NIMG*CC)     // 110336
#define NELEM ((long)ROWS_ALL*DM)  // 28,246,016

// ---------------- embedding: y = complex(x) @ complex(W)^T + b ----------------
// 8 (b,c) rows per block, 256 threads = one output channel d each.
__global__ __launch_bounds__(256) void k_emb(
    const float* __restrict__ xr, const float* __restrict__ xi,
    const float* __restrict__ Wre, const float* __restrict__ Wim,
    const float* __restrict__ bre, const float* __restrict__ bim,
    float* __restrict__ A) {
  __shared__ float sxr[8][FB];
  __shared__ float sxi[8][FB];
  int t = threadIdx.x;
  long bc0 = (long)blockIdx.x * 8;
  for (int idx = t; idx < 8 * FB; idx += 256) {
    int r = idx / FB, f = idx % FB;
    sxr[r][f] = xr[(bc0 + r) * FB + f];
    sxi[r][f] = xi[(bc0 + r) * FB + f];
  }
  __syncthreads();
  int d = t;
  float ar[8], ai[8];
#pragma unroll
  for (int r = 0; r < 8; r++) { ar[r] = 0.f; ai[r] = 0.f; }
  const float* wrp = Wre + (long)d * FB;
  const float* wip = Wim + (long)d * FB;
  for (int f = 0; f < FB; f++) {
    float wr = wrp[f];
    float wi = wip[f];
#pragma unroll
    for (int r = 0; r < 8; r++) {
      float xrv = sxr[r][f], xiv = sxi[r][f];
      ar[r] = fmaf(xrv, wr, ar[r]);
      ar[r] = fmaf(-xiv, wi, ar[r]);
      ai[r] = fmaf(xrv, wi, ai[r]);
      ai[r] = fmaf(xiv, wr, ai[r]);
    }
  }
  float br = bre[d], bi = bim[d];
#pragma unroll
  for (int r = 0; r < 8; r++) {
    long bc = bc0 + r;
    A[bc * DM + d] = ar[r] + br;                       // re image b at (c,d)
    A[(bc + (long)ROWS_RE) * DM + d] = ai[r] + bi;     // im image b+64
  }
}

// ---------------- attention (elementwise + flip) + transpose-scramble + residual
// grid (27 c-tiles, 8 d-tiles, 64 b); block (32,8). Computes o for both halves.
__global__ __launch_bounds__(256) void k_attn(const float* __restrict__ A,
                                              float* __restrict__ T) {
  __shared__ float ore[32][33];
  __shared__ float oim[32][33];
  int tx = threadIdx.x;        // 0..31
  int ty = threadIdx.y;        // 0..7
  int c0 = blockIdx.x * 32;
  int d0 = blockIdx.y * 32;
  int b  = blockIdx.z;
  const long base_re = (long)b * CC * DM;
  const long base_im = (long)(b + BB) * CC * DM;
#pragma unroll
  for (int q = 0; q < 4; q++) {
    int cl = ty + 8 * q;
    int c = c0 + cl;
    int d = d0 + tx;
    if (c < CC) {
      float qr = A[base_re + (long)c * DM + d];
      float qi = A[base_im + (long)c * DM + d];
      float kr = A[base_re + (long)(CC - 1 - c) * DM + (DM - 1 - d)];
      float ki = A[base_im + (long)(CC - 1 - c) * DM + (DM - 1 - d)];
      float asr = 0.25f * (qr * kr - qi * ki);
      float asi = 0.25f * (qr * ki - qi * kr);
      ore[cl][tx] = (asr - asi) * qr;   // v_re = v_im = y_re
      oim[cl][tx] = (asr + asi) * qr;
    }
  }
  __syncthreads();
  // scrambled position of o[c][d] is flat index d*CC + c within the image
#pragma unroll
  for (int q = 0; q < 4; q++) {
    int dl = ty + 8 * q;
    int d = d0 + dl;
    int c = c0 + tx;
    if (c < CC) {
      long flat = (long)d * CC + c;
      T[base_re + flat] = A[base_re + flat] + ore[tx][dl];
      T[base_im + flat] = A[base_im + flat] + oim[tx][dl];
    }
  }
}

// ---------------- batchnorm helpers ----------------
__global__ void k_zero(double* s) { s[threadIdx.x] = 0.0; }

__global__ __launch_bounds__(256) void k_bnstats(const float* __restrict__ P,
                                                 double* __restrict__ stats) {
  int d = threadIdx.x;
  long row0 = (long)blockIdx.x * 128;
  double s = 0.0, s2 = 0.0;
  for (int r = 0; r < 128; r++) {
    float x = P[(row0 + r) * DM + d];
    s += (double)x;
    s2 += (double)x * (double)x;
  }
  atomicAdd(&stats[d], s);
  atomicAdd(&stats[DM + d], s2);
}

__global__ void k_finalize(const double* __restrict__ stats,
                           const float* __restrict__ g, const float* __restrict__ be,
                           float* __restrict__ ss) {
  int d = threadIdx.x;
  double n = (double)ROWS_ALL;
  double m = stats[d] / n;
  double v = stats[DM + d] / n - m * m;
  float inv = (float)(1.0 / sqrt(v + 1e-5));
  float sc = g[d] * inv;
  ss[d] = sc;
  ss[DM + d] = be[d] - (float)m * sc;
}

__global__ __launch_bounds__(256) void k_bnapply(float* __restrict__ P,
                                                 const float* __restrict__ ss) {
  long i = (long)blockIdx.x * 256 + threadIdx.x;  // float4 index
  float4 x = ((float4*)P)[i];
  int q = (int)(i & 63);  // float4 index within the 256-channel row
  float4 sc = ((const float4*)ss)[q];
  float4 sh = ((const float4*)(ss + DM))[q];
  x.x = fmaf(x.x, sc.x, sh.x);
  x.y = fmaf(x.y, sc.y, sh.y);
  x.z = fmaf(x.z, sc.z, sh.z);
  x.w = fmaf(x.w, sc.w, sh.w);
  ((float4*)P)[i] = x;
}

// final bn-apply fused with the stack([re,im],-1) output layout
__global__ __launch_bounds__(256) void k_bnfinal(const float* __restrict__ A,
                                                 const float* __restrict__ ss,
                                                 float* __restrict__ out) {
  long gid = (long)blockIdx.x * 256 + threadIdx.x;  // over ROWS_RE*DM
  int d = (int)(gid & 255);
  long bc = gid >> 8;
  float sc = ss[d], sh = ss[DM + d];
  float re = A[bc * DM + d];
  float im = A[(bc + (long)ROWS_RE) * DM + d];
  float2 o;
  o.x = fmaf(re, sc, sh);
  o.y = fmaf(im, sc, sh);
  ((float2*)out)[gid] = o;
}

// ---------------- fused FF: out = src + gelu(src@W1^T + b1)@W2^T + b2 --------
// 32 rows/block, 256 threads = 64 lanes x 4 row-groups. H kept in LDS.
__global__ __launch_bounds__(256) void k_ff(
    const float* __restrict__ P, const float* __restrict__ W1,
    const float* __restrict__ b1, const float* __restrict__ W2,
    const float* __restrict__ b2, float* __restrict__ Out) {
  __shared__ float sS[32 * DM];    // 32 KB
  __shared__ float sH[32 * DFF];   // 64 KB
  int t = threadIdx.x;
  int lane = t & 63;
  int rg = t >> 6;
  int r0 = rg * 8;
  long row0 = (long)blockIdx.x * 32;

  const float4* Pv = (const float4*)(P + row0 * DM);
  float4* Sv = (float4*)sS;
#pragma unroll
  for (int i = 0; i < 8; i++) Sv[t + i * 256] = Pv[t + i * 256];
  __syncthreads();

  // FF1 + gelu -> sH
  for (int slab = 0; slab < 2; slab++) {
    float acc[8][4];
#pragma unroll
    for (int r = 0; r < 8; r++)
#pragma unroll
      for (int j = 0; j < 4; j++) acc[r][j] = 0.f;
    const float* w1p0 = W1 + (long)(slab * 256 + 0 * 64 + lane) * DM;
    const float* w1p1 = W1 + (long)(slab * 256 + 1 * 64 + lane) * DM;
    const float* w1p2 = W1 + (long)(slab * 256 + 2 * 64 + lane) * DM;
    const float* w1p3 = W1 + (long)(slab * 256 + 3 * 64 + lane) * DM;
#pragma unroll 4
    for (int k = 0; k < DM; k++) {
      float s[8];
#pragma unroll
      for (int r = 0; r < 8; r++) s[r] = sS[(r0 + r) * DM + k];
      float w0 = w1p0[k], w1 = w1p1[k], w2 = w1p2[k], w3 = w1p3[k];
#pragma unroll
      for (int r = 0; r < 8; r++) {
        acc[r][0] = fmaf(s[r], w0, acc[r][0]);
        acc[r][1] = fmaf(s[r], w1, acc[r][1]);
        acc[r][2] = fmaf(s[r], w2, acc[r][2]);
        acc[r][3] = fmaf(s[r], w3, acc[r][3]);
      }
    }
#pragma unroll
    for (int j = 0; j < 4; j++) {
      int f = slab * 256 + j * 64 + lane;
      float bb = b1[f];
#pragma unroll
      for (int r = 0; r < 8; r++) {
        float x = acc[r][j] + bb;
        float g = 0.5f * x * (1.0f + erff(x * 0.70710678118654752f));
        sH[(r0 + r) * DFF + f] = g;
      }
    }
  }
  __syncthreads();

  // FF2 + residual
  float acc2[8][4];
#pragma unroll
  for (int r = 0; r < 8; r++)
#pragma unroll
    for (int j = 0; j < 4; j++) acc2[r][j] = 0.f;
  const float* w2p0 = W2 + (long)(0 * 64 + lane) * DFF;
  const float* w2p1 = W2 + (long)(1 * 64 + lane) * DFF;
  const float* w2p2 = W2 + (long)(2 * 64 + lane) * DFF;
  const float* w2p3 = W2 + (long)(3 * 64 + lane) * DFF;
#pragma unroll 4
  for (int k = 0; k < DFF; k++) {
    float h[8];
#pragma unroll
    for (int r = 0; r < 8; r++) h[r] = sH[(r0 + r) * DFF + k];
    float w0 = w2p0[k], w1 = w2p1[k], w2 = w2p2[k], w3 = w2p3[k];
#pragma unroll
    for (int r = 0; r < 8; r++) {
      acc2[r][0] = fmaf(h[r], w0, acc2[r][0]);
      acc2[r][1] = fmaf(h[r], w1, acc2[r][1]);
      acc2[r][2] = fmaf(h[r], w2, acc2[r][2]);
      acc2[r][3] = fmaf(h[r], w3, acc2[r][3]);
    }
  }
#pragma unroll
  for (int j = 0; j < 4; j++) {
    int d = j * 64 + lane;
    float bb = b2[d];
#pragma unroll
    for (int r = 0; r < 8; r++) {
      Out[(row0 + r0 + r) * DM + d] = sS[(r0 + r) * DM + d] + acc2[r][j] + bb;
    }
  }
}

extern "C" void kernel_launch(void* const* d_in, const int* in_sizes, int n_in,
                              void* d_out, int out_size, void* d_ws, size_t ws_size,
                              hipStream_t stream) {
  const float* xr  = (const float*)d_in[0];
  const float* xi  = (const float*)d_in[1];
  const float* Wre = (const float*)d_in[2];
  const float* Wim = (const float*)d_in[3];
  const float* bre = (const float*)d_in[4];
  const float* bim = (const float*)d_in[5];
  const float* W1  = (const float*)d_in[6];
  const float* b1  = (const float*)d_in[7];
  const float* W2  = (const float*)d_in[8];
  const float* b2  = (const float*)d_in[9];
  const float* g1  = (const float*)d_in[10];
  const float* be1 = (const float*)d_in[11];
  const float* g2  = (const float*)d_in[12];
  const float* be2 = (const float*)d_in[13];

  float* A = (float*)d_ws;                                   // 113 MB activation
  double* stats = (double*)((char*)d_ws + (size_t)NELEM * 4); // 512 doubles
  float* ss = (float*)(stats + 512);                          // 512 floats
  float* T = (float*)d_out;                                   // scratch ping buffer

  k_emb<<<ROWS_RE / 8, 256, 0, stream>>>(xr, xi, Wre, Wim, bre, bim, A);

  for (int l = 0; l < 3; l++) {
    k_attn<<<dim3(27, 8, 64), dim3(32, 8), 0, stream>>>(A, T);
    k_zero<<<1, 512, 0, stream>>>(stats);
    k_bnstats<<<862, 256, 0, stream>>>(T, stats);
    k_finalize<<<1, 256, 0, stream>>>(stats, g1 + l * DM, be1 + l * DM, ss);
    k_bnapply<<<(int)(NELEM / 1024), 256, 0, stream>>>(T, ss);
    k_ff<<<ROWS_ALL / 32, 256, 0, stream>>>(T, W1 + (long)l * DFF * DM,
                                            b1 + l * DFF, W2 + (long)l * DM * DFF,
                                            b2 + l * DM, A);
    k_zero<<<1, 512, 0, stream>>>(stats);
    k_bnstats<<<862, 256, 0, stream>>>(A, stats);
    k_finalize<<<1, 256, 0, stream>>>(stats, g2 + l * DM, be2 + l * DM, ss);
    if (l < 2) {
      k_bnapply<<<(int)(NELEM / 1024), 256, 0, stream>>>(A, ss);
    } else {
      k_bnfinal<<<ROWS_RE * DM / 256, 256, 0, stream>>>(A, ss, (float*)d_out);
    }
  }
}

// Round 2
// 6524.005 us; speedup vs baseline: 1.4564x; 1.4564x over previous
//
#include <hip/hip_runtime.h>
#include <math.h>

#define BB   64
#define CC   862
#define FB   257
#define DM   256
#define DFF  512
#define NIMG 128
#define ROWS_RE (BB*CC)        // 55168
#define ROWS_ALL (NIMG*CC)     // 110336
#define NELEM ((long)ROWS_ALL*DM)  // 28,246,016

// ---------------- weight transpose: Wt[f][d] = (Wre[d][f], Wim[d][f]) --------
__global__ __launch_bounds__(256) void k_wtrans(const float* __restrict__ Wre,
                                                const float* __restrict__ Wim,
                                                float2* __restrict__ Wt) {
  int f = blockIdx.x;     // 0..256
  int d = threadIdx.x;    // 0..255
  float2 w;
  w.x = Wre[(long)d * FB + f];
  w.y = Wim[(long)d * FB + f];
  Wt[(long)f * DM + d] = w;
}

// ---------------- embedding: y = complex(x) @ complex(W)^T + b ----------------
// 16 rows/block. 256 thr = 64 lanes (4 consecutive d each) x 4 row-groups (4 rows each).
// Weights read coalesced from Wt (float2 interleaved), x broadcast from LDS.
__global__ __launch_bounds__(256) void k_emb(
    const float* __restrict__ xr, const float* __restrict__ xi,
    const float2* __restrict__ Wt,
    const float* __restrict__ bre, const float* __restrict__ bim,
    float* __restrict__ A) {
  __shared__ float sxr[16][260];
  __shared__ float sxi[16][260];
  int t = threadIdx.x;
  int lane = t & 63;
  int rg = t >> 6;
  int r0 = rg * 4;
  int d0 = lane * 4;
  long row0 = (long)blockIdx.x * 16;

  // stage x (rows are contiguous, coalesced b32 loads)
  for (int idx = t; idx < 16 * FB; idx += 256) {
    int r = idx / FB, f = idx - r * FB;
    sxr[r][f] = xr[(row0 + r) * FB + f];
    sxi[r][f] = xi[(row0 + r) * FB + f];
  }
  __syncthreads();

  float ar[4][4], ai[4][4];
#pragma unroll
  for (int rr = 0; rr < 4; rr++)
#pragma unroll
    for (int j = 0; j < 4; j++) { ar[rr][j] = 0.f; ai[rr][j] = 0.f; }

  // main loop: f in chunks of 4 (covers 0..255), tail f=256 after
  for (int f0 = 0; f0 < 256; f0 += 4) {
    float4 xr4[4], xi4[4];
#pragma unroll
    for (int rr = 0; rr < 4; rr++) {
      xr4[rr] = *(const float4*)&sxr[r0 + rr][f0];
      xi4[rr] = *(const float4*)&sxi[r0 + rr][f0];
    }
#pragma unroll
    for (int fl = 0; fl < 4; fl++) {
      const float4* wp = (const float4*)(Wt + (long)(f0 + fl) * DM + d0);
      float4 wA = wp[0];   // (re,im) for d0, d0+1
      float4 wB = wp[1];   // (re,im) for d0+2, d0+3
#pragma unroll
      for (int rr = 0; rr < 4; rr++) {
        float xrv = ((const float*)&xr4[rr])[fl];
        float xiv = ((const float*)&xi4[rr])[fl];
        ar[rr][0] = fmaf(xrv, wA.x, ar[rr][0]); ar[rr][0] = fmaf(-xiv, wA.y, ar[rr][0]);
        ai[rr][0] = fmaf(xrv, wA.y, ai[rr][0]); ai[rr][0] = fmaf( xiv, wA.x, ai[rr][0]);
        ar[rr][1] = fmaf(xrv, wA.z, ar[rr][1]); ar[rr][1] = fmaf(-xiv, wA.w, ar[rr][1]);
        ai[rr][1] = fmaf(xrv, wA.w, ai[rr][1]); ai[rr][1] = fmaf( xiv, wA.z, ai[rr][1]);
        ar[rr][2] = fmaf(xrv, wB.x, ar[rr][2]); ar[rr][2] = fmaf(-xiv, wB.y, ar[rr][2]);
        ai[rr][2] = fmaf(xrv, wB.y, ai[rr][2]); ai[rr][2] = fmaf( xiv, wB.x, ai[rr][2]);
        ar[rr][3] = fmaf(xrv, wB.z, ar[rr][3]); ar[rr][3] = fmaf(-xiv, wB.w, ar[rr][3]);
        ai[rr][3] = fmaf(xrv, wB.w, ai[rr][3]); ai[rr][3] = fmaf( xiv, wB.z, ai[rr][3]);
      }
    }
  }
  // tail f = 256
  {
    const float4* wp = (const float4*)(Wt + (long)256 * DM + d0);
    float4 wA = wp[0];
    float4 wB = wp[1];
#pragma unroll
    for (int rr = 0; rr < 4; rr++) {
      float xrv = sxr[r0 + rr][256];
      float xiv = sxi[r0 + rr][256];
      ar[rr][0] = fmaf(xrv, wA.x, ar[rr][0]); ar[rr][0] = fmaf(-xiv, wA.y, ar[rr][0]);
      ai[rr][0] = fmaf(xrv, wA.y, ai[rr][0]); ai[rr][0] = fmaf( xiv, wA.x, ai[rr][0]);
      ar[rr][1] = fmaf(xrv, wA.z, ar[rr][1]); ar[rr][1] = fmaf(-xiv, wA.w, ar[rr][1]);
      ai[rr][1] = fmaf(xrv, wA.w, ai[rr][1]); ai[rr][1] = fmaf( xiv, wA.z, ai[rr][1]);
      ar[rr][2] = fmaf(xrv, wB.x, ar[rr][2]); ar[rr][2] = fmaf(-xiv, wB.y, ar[rr][2]);
      ai[rr][2] = fmaf(xrv, wB.y, ai[rr][2]); ai[rr][2] = fmaf( xiv, wB.x, ai[rr][2]);
      ar[rr][3] = fmaf(xrv, wB.z, ar[rr][3]); ar[rr][3] = fmaf(-xiv, wB.w, ar[rr][3]);
      ai[rr][3] = fmaf(xrv, wB.w, ai[rr][3]); ai[rr][3] = fmaf( xiv, wB.z, ai[rr][3]);
    }
  }

  float4 brv = ((const float4*)bre)[lane];
  float4 biv = ((const float4*)bim)[lane];
#pragma unroll
  for (int rr = 0; rr < 4; rr++) {
    long bc = row0 + r0 + rr;
    float4 o;
    o.x = ar[rr][0] + brv.x; o.y = ar[rr][1] + brv.y;
    o.z = ar[rr][2] + brv.z; o.w = ar[rr][3] + brv.w;
    *(float4*)(A + bc * DM + d0) = o;
    float4 oi;
    oi.x = ai[rr][0] + biv.x; oi.y = ai[rr][1] + biv.y;
    oi.z = ai[rr][2] + biv.z; oi.w = ai[rr][3] + biv.w;
    *(float4*)(A + (bc + (long)ROWS_RE) * DM + d0) = oi;
  }
}

// ---------------- attention (elementwise + flip) + transpose-scramble + residual
__global__ __launch_bounds__(256) void k_attn(const float* __restrict__ A,
                                              float* __restrict__ T) {
  __shared__ float ore[32][33];
  __shared__ float oim[32][33];
  int tx = threadIdx.x;        // 0..31
  int ty = threadIdx.y;        // 0..7
  int c0 = blockIdx.x * 32;
  int d0 = blockIdx.y * 32;
  int b  = blockIdx.z;
  const long base_re = (long)b * CC * DM;
  const long base_im = (long)(b + BB) * CC * DM;
#pragma unroll
  for (int q = 0; q < 4; q++) {
    int cl = ty + 8 * q;
    int c = c0 + cl;
    int d = d0 + tx;
    if (c < CC) {
      float qr = A[base_re + (long)c * DM + d];
      float qi = A[base_im + (long)c * DM + d];
      float kr = A[base_re + (long)(CC - 1 - c) * DM + (DM - 1 - d)];
      float ki = A[base_im + (long)(CC - 1 - c) * DM + (DM - 1 - d)];
      float asr = 0.25f * (qr * kr - qi * ki);
      float asi = 0.25f * (qr * ki - qi * kr);
      ore[cl][tx] = (asr - asi) * qr;   // v_re = v_im = y_re
      oim[cl][tx] = (asr + asi) * qr;
    }
  }
  __syncthreads();
  // scrambled position of o[c][d] is flat index d*CC + c within the image
#pragma unroll
  for (int q = 0; q < 4; q++) {
    int dl = ty + 8 * q;
    int d = d0 + dl;
    int c = c0 + tx;
    if (c < CC) {
      long flat = (long)d * CC + c;
      T[base_re + flat] = A[base_re + flat] + ore[tx][dl];
      T[base_im + flat] = A[base_im + flat] + oim[tx][dl];
    }
  }
}

// ---------------- batchnorm helpers ----------------
__global__ void k_zero(double* s) { s[threadIdx.x] = 0.0; }

__global__ __launch_bounds__(256) void k_bnstats(const float* __restrict__ P,
                                                 double* __restrict__ stats) {
  int d = threadIdx.x;
  long row0 = (long)blockIdx.x * 128;
  double s = 0.0, s2 = 0.0;
  for (int r = 0; r < 128; r++) {
    float x = P[(row0 + r) * DM + d];
    s += (double)x;
    s2 += (double)x * (double)x;
  }
  atomicAdd(&stats[d], s);
  atomicAdd(&stats[DM + d], s2);
}

__global__ void k_finalize(const double* __restrict__ stats,
                           const float* __restrict__ g, const float* __restrict__ be,
                           float* __restrict__ ss) {
  int d = threadIdx.x;
  double n = (double)ROWS_ALL;
  double m = stats[d] / n;
  double v = stats[DM + d] / n - m * m;
  float inv = (float)(1.0 / sqrt(v + 1e-5));
  float sc = g[d] * inv;
  ss[d] = sc;
  ss[DM + d] = be[d] - (float)m * sc;
}

__global__ __launch_bounds__(256) void k_bnapply(float* __restrict__ P,
                                                 const float* __restrict__ ss) {
  long i = (long)blockIdx.x * 256 + threadIdx.x;  // float4 index
  float4 x = ((float4*)P)[i];
  int q = (int)(i & 63);  // float4 index within the 256-channel row
  float4 sc = ((const float4*)ss)[q];
  float4 sh = ((const float4*)(ss + DM))[q];
  x.x = fmaf(x.x, sc.x, sh.x);
  x.y = fmaf(x.y, sc.y, sh.y);
  x.z = fmaf(x.z, sc.z, sh.z);
  x.w = fmaf(x.w, sc.w, sh.w);
  ((float4*)P)[i] = x;
}

// final bn-apply fused with the stack([re,im],-1) output layout
__global__ __launch_bounds__(256) void k_bnfinal(const float* __restrict__ A,
                                                 const float* __restrict__ ss,
                                                 float* __restrict__ out) {
  long gid = (long)blockIdx.x * 256 + threadIdx.x;  // over ROWS_RE*DM
  int d = (int)(gid & 255);
  long bc = gid >> 8;
  float sc = ss[d], sh = ss[DM + d];
  float re = A[bc * DM + d];
  float im = A[(bc + (long)ROWS_RE) * DM + d];
  float2 o;
  o.x = fmaf(re, sc, sh);
  o.y = fmaf(im, sc, sh);
  ((float2*)out)[gid] = o;
}

// ---------------- fused FF: out = src + gelu(src@W1^T + b1)@W2^T + b2 --------
__global__ __launch_bounds__(256) void k_ff(
    const float* __restrict__ P, const float* __restrict__ W1,
    const float* __restrict__ b1, const float* __restrict__ W2,
    const float* __restrict__ b2, float* __restrict__ Out) {
  __shared__ float sS[32 * DM];    // 32 KB
  __shared__ float sH[32 * DFF];   // 64 KB
  int t = threadIdx.x;
  int lane = t & 63;
  int rg = t >> 6;
  int r0 = rg * 8;
  long row0 = (long)blockIdx.x * 32;

  const float4* Pv = (const float4*)(P + row0 * DM);
  float4* Sv = (float4*)sS;
#pragma unroll
  for (int i = 0; i < 8; i++) Sv[t + i * 256] = Pv[t + i * 256];
  __syncthreads();

  // FF1 + gelu -> sH
  for (int slab = 0; slab < 2; slab++) {
    float acc[8][4];
#pragma unroll
    for (int r = 0; r < 8; r++)
#pragma unroll
      for (int j = 0; j < 4; j++) acc[r][j] = 0.f;
    const float* w1p0 = W1 + (long)(slab * 256 + 0 * 64 + lane) * DM;
    const float* w1p1 = W1 + (long)(slab * 256 + 1 * 64 + lane) * DM;
    const float* w1p2 = W1 + (long)(slab * 256 + 2 * 64 + lane) * DM;
    const float* w1p3 = W1 + (long)(slab * 256 + 3 * 64 + lane) * DM;
#pragma unroll 4
    for (int k = 0; k < DM; k++) {
      float s[8];
#pragma unroll
      for (int r = 0; r < 8; r++) s[r] = sS[(r0 + r) * DM + k];
      float w0 = w1p0[k], w1 = w1p1[k], w2 = w1p2[k], w3 = w1p3[k];
#pragma unroll
      for (int r = 0; r < 8; r++) {
        acc[r][0] = fmaf(s[r], w0, acc[r][0]);
        acc[r][1] = fmaf(s[r], w1, acc[r][1]);
        acc[r][2] = fmaf(s[r], w2, acc[r][2]);
        acc[r][3] = fmaf(s[r], w3, acc[r][3]);
      }
    }
#pragma unroll
    for (int j = 0; j < 4; j++) {
      int f = slab * 256 + j * 64 + lane;
      float bb = b1[f];
#pragma unroll
      for (int r = 0; r < 8; r++) {
        float x = acc[r][j] + bb;
        float g = 0.5f * x * (1.0f + erff(x * 0.70710678118654752f));
        sH[(r0 + r) * DFF + f] = g;
      }
    }
  }
  __syncthreads();

  // FF2 + residual
  float acc2[8][4];
#pragma unroll
  for (int r = 0; r < 8; r++)
#pragma unroll
    for (int j = 0; j < 4; j++) acc2[r][j] = 0.f;
  const float* w2p0 = W2 + (long)(0 * 64 + lane) * DFF;
  const float* w2p1 = W2 + (long)(1 * 64 + lane) * DFF;
  const float* w2p2 = W2 + (long)(2 * 64 + lane) * DFF;
  const float* w2p3 = W2 + (long)(3 * 64 + lane) * DFF;
#pragma unroll 4
  for (int k = 0; k < DFF; k++) {
    float h[8];
#pragma unroll
    for (int r = 0; r < 8; r++) h[r] = sH[(r0 + r) * DFF + k];
    float w0 = w2p0[k], w1 = w2p1[k], w2 = w2p2[k], w3 = w2p3[k];
#pragma unroll
    for (int r = 0; r < 8; r++) {
      acc2[r][0] = fmaf(h[r], w0, acc2[r][0]);
      acc2[r][1] = fmaf(h[r], w1, acc2[r][1]);
      acc2[r][2] = fmaf(h[r], w2, acc2[r][2]);
      acc2[r][3] = fmaf(h[r], w3, acc2[r][3]);
    }
  }
#pragma unroll
  for (int j = 0; j < 4; j++) {
    int d = j * 64 + lane;
    float bb = b2[d];
#pragma unroll
    for (int r = 0; r < 8; r++) {
      Out[(row0 + r0 + r) * DM + d] = sS[(r0 + r) * DM + d] + acc2[r][j] + bb;
    }
  }
}

extern "C" void kernel_launch(void* const* d_in, const int* in_sizes, int n_in,
                              void* d_out, int out_size, void* d_ws, size_t ws_size,
                              hipStream_t stream) {
  const float* xr  = (const float*)d_in[0];
  const float* xi  = (const float*)d_in[1];
  const float* Wre = (const float*)d_in[2];
  const float* Wim = (const float*)d_in[3];
  const float* bre = (const float*)d_in[4];
  const float* bim = (const float*)d_in[5];
  const float* W1  = (const float*)d_in[6];
  const float* b1  = (const float*)d_in[7];
  const float* W2  = (const float*)d_in[8];
  const float* b2  = (const float*)d_in[9];
  const float* g1  = (const float*)d_in[10];
  const float* be1 = (const float*)d_in[11];
  const float* g2  = (const float*)d_in[12];
  const float* be2 = (const float*)d_in[13];

  float* A = (float*)d_ws;                                   // 113 MB activation
  double* stats = (double*)((char*)d_ws + (size_t)NELEM * 4); // 512 doubles
  float* ss = (float*)(stats + 512);                          // 512 floats
  float* T = (float*)d_out;                                   // scratch ping buffer
  float2* Wt = (float2*)d_out;                                // 526 KB, used only before first k_attn

  k_wtrans<<<FB, 256, 0, stream>>>(Wre, Wim, Wt);
  k_emb<<<ROWS_RE / 16, 256, 0, stream>>>(xr, xi, Wt, bre, bim, A);

  for (int l = 0; l < 3; l++) {
    k_attn<<<dim3(27, 8, 64), dim3(32, 8), 0, stream>>>(A, T);
    k_zero<<<1, 512, 0, stream>>>(stats);
    k_bnstats<<<862, 256, 0, stream>>>(T, stats);
    k_finalize<<<1, 256, 0, stream>>>(stats, g1 + l * DM, be1 + l * DM, ss);
    k_bnapply<<<(int)(NELEM / 1024), 256, 0, stream>>>(T, ss);
    k_ff<<<ROWS_ALL / 32, 256, 0, stream>>>(T, W1 + (long)l * DFF * DM,
                                            b1 + l * DFF, W2 + (long)l * DM * DFF,
                                            b2 + l * DM, A);
    k_zero<<<1, 512, 0, stream>>>(stats);
    k_bnstats<<<862, 256, 0, stream>>>(A, stats);
    k_finalize<<<1, 256, 0, stream>>>(stats, g2 + l * DM, be2 + l * DM, ss);
    if (l < 2) {
      k_bnapply<<<(int)(NELEM / 1024), 256, 0, stream>>>(A, ss);
    } else {
      k_bnfinal<<<ROWS_RE * DM / 256, 256, 0, stream>>>(A, ss, (float*)d_out);
    }
  }
}

// Round 3
// 2418.554 us; speedup vs baseline: 3.9285x; 2.6975x over previous
//
#include <hip/hip_runtime.h>
#include <hip/hip_bf16.h>
#include <math.h>

#define BB   64
#define CC   862
#define FB   257
#define DM   256
#define DFF  512
#define NIMG 128
#define ROWS_RE (BB*CC)        // 55168
#define ROWS_ALL (NIMG*CC)     // 110336
#define NELEM ((long)ROWS_ALL*DM)  // 28,246,016

typedef __bf16 bf16x8 __attribute__((ext_vector_type(8)));
typedef float  f32x4  __attribute__((ext_vector_type(4)));

// ---------------- weight transpose: Wt[f][d] = (Wre[d][f], Wim[d][f]) --------
__global__ __launch_bounds__(256) void k_wtrans(const float* __restrict__ Wre,
                                                const float* __restrict__ Wim,
                                                float2* __restrict__ Wt) {
  int f = blockIdx.x;     // 0..256
  int d = threadIdx.x;    // 0..255
  float2 w;
  w.x = Wre[(long)d * FB + f];
  w.y = Wim[(long)d * FB + f];
  Wt[(long)f * DM + d] = w;
}

// ---------------- embedding: y = complex(x) @ complex(W)^T + b ----------------
__global__ __launch_bounds__(256) void k_emb(
    const float* __restrict__ xr, const float* __restrict__ xi,
    const float2* __restrict__ Wt,
    const float* __restrict__ bre, const float* __restrict__ bim,
    float* __restrict__ A) {
  __shared__ float sxr[16][260];
  __shared__ float sxi[16][260];
  int t = threadIdx.x;
  int lane = t & 63;
  int rg = t >> 6;
  int r0 = rg * 4;
  int d0 = lane * 4;
  long row0 = (long)blockIdx.x * 16;

  for (int idx = t; idx < 16 * FB; idx += 256) {
    int r = idx / FB, f = idx - r * FB;
    sxr[r][f] = xr[(row0 + r) * FB + f];
    sxi[r][f] = xi[(row0 + r) * FB + f];
  }
  __syncthreads();

  float ar[4][4], ai[4][4];
#pragma unroll
  for (int rr = 0; rr < 4; rr++)
#pragma unroll
    for (int j = 0; j < 4; j++) { ar[rr][j] = 0.f; ai[rr][j] = 0.f; }

  for (int f0 = 0; f0 < 256; f0 += 4) {
    float4 xr4[4], xi4[4];
#pragma unroll
    for (int rr = 0; rr < 4; rr++) {
      xr4[rr] = *(const float4*)&sxr[r0 + rr][f0];
      xi4[rr] = *(const float4*)&sxi[r0 + rr][f0];
    }
#pragma unroll
    for (int fl = 0; fl < 4; fl++) {
      const float4* wp = (const float4*)(Wt + (long)(f0 + fl) * DM + d0);
      float4 wA = wp[0];
      float4 wB = wp[1];
#pragma unroll
      for (int rr = 0; rr < 4; rr++) {
        float xrv = ((const float*)&xr4[rr])[fl];
        float xiv = ((const float*)&xi4[rr])[fl];
        ar[rr][0] = fmaf(xrv, wA.x, ar[rr][0]); ar[rr][0] = fmaf(-xiv, wA.y, ar[rr][0]);
        ai[rr][0] = fmaf(xrv, wA.y, ai[rr][0]); ai[rr][0] = fmaf( xiv, wA.x, ai[rr][0]);
        ar[rr][1] = fmaf(xrv, wA.z, ar[rr][1]); ar[rr][1] = fmaf(-xiv, wA.w, ar[rr][1]);
        ai[rr][1] = fmaf(xrv, wA.w, ai[rr][1]); ai[rr][1] = fmaf( xiv, wA.z, ai[rr][1]);
        ar[rr][2] = fmaf(xrv, wB.x, ar[rr][2]); ar[rr][2] = fmaf(-xiv, wB.y, ar[rr][2]);
        ai[rr][2] = fmaf(xrv, wB.y, ai[rr][2]); ai[rr][2] = fmaf( xiv, wB.x, ai[rr][2]);
        ar[rr][3] = fmaf(xrv, wB.z, ar[rr][3]); ar[rr][3] = fmaf(-xiv, wB.w, ar[rr][3]);
        ai[rr][3] = fmaf(xrv, wB.w, ai[rr][3]); ai[rr][3] = fmaf( xiv, wB.z, ai[rr][3]);
      }
    }
  }
  {
    const float4* wp = (const float4*)(Wt + (long)256 * DM + d0);
    float4 wA = wp[0];
    float4 wB = wp[1];
#pragma unroll
    for (int rr = 0; rr < 4; rr++) {
      float xrv = sxr[r0 + rr][256];
      float xiv = sxi[r0 + rr][256];
      ar[rr][0] = fmaf(xrv, wA.x, ar[rr][0]); ar[rr][0] = fmaf(-xiv, wA.y, ar[rr][0]);
      ai[rr][0] = fmaf(xrv, wA.y, ai[rr][0]); ai[rr][0] = fmaf( xiv, wA.x, ai[rr][0]);
      ar[rr][1] = fmaf(xrv, wA.z, ar[rr][1]); ar[rr][1] = fmaf(-xiv, wA.w, ar[rr][1]);
      ai[rr][1] = fmaf(xrv, wA.w, ai[rr][1]); ai[rr][1] = fmaf( xiv, wA.z, ai[rr][1]);
      ar[rr][2] = fmaf(xrv, wB.x, ar[rr][2]); ar[rr][2] = fmaf(-xiv, wB.y, ar[rr][2]);
      ai[rr][2] = fmaf(xrv, wB.y, ai[rr][2]); ai[rr][2] = fmaf( xiv, wB.x, ai[rr][2]);
      ar[rr][3] = fmaf(xrv, wB.z, ar[rr][3]); ar[rr][3] = fmaf(-xiv, wB.w, ar[rr][3]);
      ai[rr][3] = fmaf(xrv, wB.w, ai[rr][3]); ai[rr][3] = fmaf( xiv, wB.z, ai[rr][3]);
    }
  }

  float4 brv = ((const float4*)bre)[lane];
  float4 biv = ((const float4*)bim)[lane];
#pragma unroll
  for (int rr = 0; rr < 4; rr++) {
    long bc = row0 + r0 + rr;
    float4 o;
    o.x = ar[rr][0] + brv.x; o.y = ar[rr][1] + brv.y;
    o.z = ar[rr][2] + brv.z; o.w = ar[rr][3] + brv.w;
    *(float4*)(A + bc * DM + d0) = o;
    float4 oi;
    oi.x = ai[rr][0] + biv.x; oi.y = ai[rr][1] + biv.y;
    oi.z = ai[rr][2] + biv.z; oi.w = ai[rr][3] + biv.w;
    *(float4*)(A + (bc + (long)ROWS_RE) * DM + d0) = oi;
  }
}

// ---------------- attention (elementwise + flip) + transpose-scramble + residual
__global__ __launch_bounds__(256) void k_attn(const float* __restrict__ A,
                                              float* __restrict__ T) {
  __shared__ float ore[32][33];
  __shared__ float oim[32][33];
  int tx = threadIdx.x;
  int ty = threadIdx.y;
  int c0 = blockIdx.x * 32;
  int d0 = blockIdx.y * 32;
  int b  = blockIdx.z;
  const long base_re = (long)b * CC * DM;
  const long base_im = (long)(b + BB) * CC * DM;
#pragma unroll
  for (int q = 0; q < 4; q++) {
    int cl = ty + 8 * q;
    int c = c0 + cl;
    int d = d0 + tx;
    if (c < CC) {
      float qr = A[base_re + (long)c * DM + d];
      float qi = A[base_im + (long)c * DM + d];
      float kr = A[base_re + (long)(CC - 1 - c) * DM + (DM - 1 - d)];
      float ki = A[base_im + (long)(CC - 1 - c) * DM + (DM - 1 - d)];
      float asr = 0.25f * (qr * kr - qi * ki);
      float asi = 0.25f * (qr * ki - qi * kr);
      ore[cl][tx] = (asr - asi) * qr;
      oim[cl][tx] = (asr + asi) * qr;
    }
  }
  __syncthreads();
#pragma unroll
  for (int q = 0; q < 4; q++) {
    int dl = ty + 8 * q;
    int d = d0 + dl;
    int c = c0 + tx;
    if (c < CC) {
      long flat = (long)d * CC + c;
      T[base_re + flat] = A[base_re + flat] + ore[tx][dl];
      T[base_im + flat] = A[base_im + flat] + oim[tx][dl];
    }
  }
}

// ---------------- batchnorm helpers ----------------
__global__ void k_zero(double* s) { s[threadIdx.x] = 0.0; }

__global__ __launch_bounds__(256) void k_bnstats(const float* __restrict__ P,
                                                 double* __restrict__ stats) {
  int d = threadIdx.x;
  long row0 = (long)blockIdx.x * 128;
  double s = 0.0, s2 = 0.0;
  for (int r = 0; r < 128; r++) {
    float x = P[(row0 + r) * DM + d];
    s += (double)x;
    s2 += (double)x * (double)x;
  }
  atomicAdd(&stats[d], s);
  atomicAdd(&stats[DM + d], s2);
}

__global__ void k_finalize(const double* __restrict__ stats,
                           const float* __restrict__ g, const float* __restrict__ be,
                           float* __restrict__ ss) {
  int d = threadIdx.x;
  double n = (double)ROWS_ALL;
  double m = stats[d] / n;
  double v = stats[DM + d] / n - m * m;
  float inv = (float)(1.0 / sqrt(v + 1e-5));
  float sc = g[d] * inv;
  ss[d] = sc;
  ss[DM + d] = be[d] - (float)m * sc;
}

__global__ __launch_bounds__(256) void k_bnapply(float* __restrict__ P,
                                                 const float* __restrict__ ss) {
  long i = (long)blockIdx.x * 256 + threadIdx.x;
  float4 x = ((float4*)P)[i];
  int q = (int)(i & 63);
  float4 sc = ((const float4*)ss)[q];
  float4 sh = ((const float4*)(ss + DM))[q];
  x.x = fmaf(x.x, sc.x, sh.x);
  x.y = fmaf(x.y, sc.y, sh.y);
  x.z = fmaf(x.z, sc.z, sh.z);
  x.w = fmaf(x.w, sc.w, sh.w);
  ((float4*)P)[i] = x;
}

__global__ __launch_bounds__(256) void k_bnfinal(const float* __restrict__ A,
                                                 const float* __restrict__ ss,
                                                 float* __restrict__ out) {
  long gid = (long)blockIdx.x * 256 + threadIdx.x;
  int d = (int)(gid & 255);
  long bc = gid >> 8;
  float sc = ss[d], sh = ss[DM + d];
  float re = A[bc * DM + d];
  float im = A[(bc + (long)ROWS_RE) * DM + d];
  float2 o;
  o.x = fmaf(re, sc, sh);
  o.y = fmaf(im, sc, sh);
  ((float2*)out)[gid] = o;
}

// ---------------- MFMA fused FF: out = src + gelu(src@W1^T + b1)@W2^T + b2 ---
// 32 rows/block, 4 waves. Wave w owns N-slice [w*128,(w+1)*128) in FF1 and
// [w*64,(w+1)*64) in FF2 -> each weight element read once per block (f32,
// L2-resident), converted to bf16 inline. S and H tiles live in LDS as bf16.
// LDS = 16.5 + 32.5 = 49 KB -> 3 blocks/CU.
#define PS 264   // sS pitch in bf16 (+8 pad: 2-way banks = free)
#define PH 520   // sH pitch in bf16

__global__ __launch_bounds__(256, 3) void k_ffm(
    const float* __restrict__ P, const float* __restrict__ W1,
    const float* __restrict__ b1, const float* __restrict__ W2,
    const float* __restrict__ b2, float* __restrict__ Out) {
  __shared__ __bf16 sS[32 * PS];
  __shared__ __bf16 sH[32 * PH];
  int t = threadIdx.x;
  int lane = t & 63;
  int w = t >> 6;
  int half = lane >> 4;     // quad index 0..3
  int l16 = lane & 15;
  long row0 = (long)blockIdx.x * 32;

  // ---- stage S tile (f32 -> bf16) ----
  {
    const float4* Pv = (const float4*)(P + row0 * DM);
#pragma unroll
    for (int i = 0; i < 8; i++) {
      int v = t + i * 256;       // 2048 float4s = 32 rows x 64
      int r = v >> 6, k4 = v & 63;
      float4 x = Pv[(long)r * 64 + k4];
      __bf16* dst = &sS[r * PS + k4 * 4];
      dst[0] = (__bf16)x.x; dst[1] = (__bf16)x.y;
      dst[2] = (__bf16)x.z; dst[3] = (__bf16)x.w;
    }
  }
  __syncthreads();

  // ---- FF1: H = gelu(S @ W1^T + b1), K=256 ----
  f32x4 acc[2][8];
#pragma unroll
  for (int mt = 0; mt < 2; mt++)
#pragma unroll
    for (int j = 0; j < 8; j++) acc[mt][j] = (f32x4){0.f, 0.f, 0.f, 0.f};

  for (int kt = 0; kt < 8; kt++) {
    int kb = kt * 32 + half * 8;
    bf16x8 a0 = *(const bf16x8*)&sS[l16 * PS + kb];
    bf16x8 a1 = *(const bf16x8*)&sS[(16 + l16) * PS + kb];
    const float* wrow = W1 + (long)(w * 128 + l16) * DM + kb;
#pragma unroll
    for (int j = 0; j < 8; j++) {
      const float* wp = wrow + (long)j * 16 * DM;
      float4 wa = *(const float4*)wp;
      float4 wb = *(const float4*)(wp + 4);
      bf16x8 bf;
      bf[0] = (__bf16)wa.x; bf[1] = (__bf16)wa.y; bf[2] = (__bf16)wa.z; bf[3] = (__bf16)wa.w;
      bf[4] = (__bf16)wb.x; bf[5] = (__bf16)wb.y; bf[6] = (__bf16)wb.z; bf[7] = (__bf16)wb.w;
      acc[0][j] = __builtin_amdgcn_mfma_f32_16x16x32_bf16(a0, bf, acc[0][j], 0, 0, 0);
      acc[1][j] = __builtin_amdgcn_mfma_f32_16x16x32_bf16(a1, bf, acc[1][j], 0, 0, 0);
    }
  }

  // gelu (tanh form) + store H to LDS as bf16
  {
    float b1v[8];
#pragma unroll
    for (int j = 0; j < 8; j++) b1v[j] = b1[w * 128 + j * 16 + l16];
#pragma unroll
    for (int mt = 0; mt < 2; mt++)
#pragma unroll
      for (int j = 0; j < 8; j++) {
        int f = w * 128 + j * 16 + l16;
#pragma unroll
        for (int r = 0; r < 4; r++) {
          float x = acc[mt][j][r] + b1v[j];
          float u = x * (0.7978845608f + 0.0356774081f * x * x);
          float g = x / (1.0f + __expf(-2.0f * u));   // x * sigmoid(2u)
          int m = mt * 16 + half * 4 + r;
          sH[m * PH + f] = (__bf16)g;
        }
      }
  }
  __syncthreads();

  // ---- FF2: out = S + H @ W2^T + b2, K=512 ----
  f32x4 acc2[2][4];
#pragma unroll
  for (int mt = 0; mt < 2; mt++)
#pragma unroll
    for (int j = 0; j < 4; j++) acc2[mt][j] = (f32x4){0.f, 0.f, 0.f, 0.f};

  for (int kt = 0; kt < 16; kt++) {
    int kb = kt * 32 + half * 8;
    bf16x8 a0 = *(const bf16x8*)&sH[l16 * PH + kb];
    bf16x8 a1 = *(const bf16x8*)&sH[(16 + l16) * PH + kb];
    const float* wrow = W2 + (long)(w * 64 + l16) * DFF + kb;
#pragma unroll
    for (int j = 0; j < 4; j++) {
      const float* wp = wrow + (long)j * 16 * DFF;
      float4 wa = *(const float4*)wp;
      float4 wb = *(const float4*)(wp + 4);
      bf16x8 bf;
      bf[0] = (__bf16)wa.x; bf[1] = (__bf16)wa.y; bf[2] = (__bf16)wa.z; bf[3] = (__bf16)wa.w;
      bf[4] = (__bf16)wb.x; bf[5] = (__bf16)wb.y; bf[6] = (__bf16)wb.z; bf[7] = (__bf16)wb.w;
      acc2[0][j] = __builtin_amdgcn_mfma_f32_16x16x32_bf16(a0, bf, acc2[0][j], 0, 0, 0);
      acc2[1][j] = __builtin_amdgcn_mfma_f32_16x16x32_bf16(a1, bf, acc2[1][j], 0, 0, 0);
    }
  }

  // epilogue: residual (f32 re-read from P) + bias, scattered f32 stores
  {
    float b2v[4];
#pragma unroll
    for (int j = 0; j < 4; j++) b2v[j] = b2[w * 64 + j * 16 + l16];
#pragma unroll
    for (int mt = 0; mt < 2; mt++)
#pragma unroll
      for (int j = 0; j < 4; j++) {
        int d = w * 64 + j * 16 + l16;
#pragma unroll
        for (int r = 0; r < 4; r++) {
          int m = mt * 16 + half * 4 + r;
          long idx = (row0 + m) * DM + d;
          Out[idx] = P[idx] + acc2[mt][j][r] + b2v[j];
        }
      }
  }
}

extern "C" void kernel_launch(void* const* d_in, const int* in_sizes, int n_in,
                              void* d_out, int out_size, void* d_ws, size_t ws_size,
                              hipStream_t stream) {
  const float* xr  = (const float*)d_in[0];
  const float* xi  = (const float*)d_in[1];
  const float* Wre = (const float*)d_in[2];
  const float* Wim = (const float*)d_in[3];
  const float* bre = (const float*)d_in[4];
  const float* bim = (const float*)d_in[5];
  const float* W1  = (const float*)d_in[6];
  const float* b1  = (const float*)d_in[7];
  const float* W2  = (const float*)d_in[8];
  const float* b2  = (const float*)d_in[9];
  const float* g1  = (const float*)d_in[10];
  const float* be1 = (const float*)d_in[11];
  const float* g2  = (const float*)d_in[12];
  const float* be2 = (const float*)d_in[13];

  float* A = (float*)d_ws;
  double* stats = (double*)((char*)d_ws + (size_t)NELEM * 4);
  float* ss = (float*)(stats + 512);
  float* T = (float*)d_out;
  float2* Wt = (float2*)d_out;   // used only before first k_attn

  k_wtrans<<<FB, 256, 0, stream>>>(Wre, Wim, Wt);
  k_emb<<<ROWS_RE / 16, 256, 0, stream>>>(xr, xi, Wt, bre, bim, A);

  for (int l = 0; l < 3; l++) {
    k_attn<<<dim3(27, 8, 64), dim3(32, 8), 0, stream>>>(A, T);
    k_zero<<<1, 512, 0, stream>>>(stats);
    k_bnstats<<<862, 256, 0, stream>>>(T, stats);
    k_finalize<<<1, 256, 0, stream>>>(stats, g1 + l * DM, be1 + l * DM, ss);
    k_bnapply<<<(int)(NELEM / 1024), 256, 0, stream>>>(T, ss);
    k_ffm<<<ROWS_ALL / 32, 256, 0, stream>>>(T, W1 + (long)l * DFF * DM,
                                             b1 + l * DFF, W2 + (long)l * DM * DFF,
                                             b2 + l * DM, A);
    k_zero<<<1, 512, 0, stream>>>(stats);
    k_bnstats<<<862, 256, 0, stream>>>(A, stats);
    k_finalize<<<1, 256, 0, stream>>>(stats, g2 + l * DM, be2 + l * DM, ss);
    if (l < 2) {
      k_bnapply<<<(int)(NELEM / 1024), 256, 0, stream>>>(A, ss);
    } else {
      k_bnfinal<<<ROWS_RE * DM / 256, 256, 0, stream>>>(A, ss, (float*)d_out);
    }
  }
}